// Round 1
// baseline (89127.258 us; speedup 1.0000x reference)
//
#include <hip/hip_runtime.h>
#include <math.h>

#define Bc 16
#define Tc 2048
#define Dc 512
#define Hc 1024
#define Rc 16

// ---------------------------------------------------------------------------
// GEMM: out[M,1024] = X[M,512] @ W[512,1024], M = 32768.
// BM=128, BN=64, BK=16, 256 threads, 8x4 micro-tile per thread.
// ---------------------------------------------------------------------------
__global__ __launch_bounds__(256) void gemm_xw(const float* __restrict__ X,
                                               const float* __restrict__ W,
                                               float* __restrict__ out)
{
    __shared__ float As[16][128];
    __shared__ float Bs[16][64];
    const int tid = threadIdx.x;
    const int m0 = blockIdx.x * 128;
    const int n0 = blockIdx.y * 64;
    const int tx = tid & 15, ty = tid >> 4;
    const int am = tid >> 2, ak = (tid & 3) * 4;   // A-load: 2 rows (am, am+64), 4 k's
    const int bk = tid >> 4, bn = (tid & 15) * 4;  // B-load: row bk, 4 n's
    float acc[8][4] = {};
    for (int k0 = 0; k0 < 512; k0 += 16) {
        if (k0) __syncthreads();
        float4 a0 = *(const float4*)&X[(size_t)(m0 + am) * 512 + k0 + ak];
        float4 a1 = *(const float4*)&X[(size_t)(m0 + am + 64) * 512 + k0 + ak];
        float4 bv = *(const float4*)&W[(size_t)(k0 + bk) * 1024 + n0 + bn];
        As[ak + 0][am] = a0.x; As[ak + 1][am] = a0.y;
        As[ak + 2][am] = a0.z; As[ak + 3][am] = a0.w;
        As[ak + 0][am + 64] = a1.x; As[ak + 1][am + 64] = a1.y;
        As[ak + 2][am + 64] = a1.z; As[ak + 3][am + 64] = a1.w;
        *(float4*)&Bs[bk][bn] = bv;
        __syncthreads();
        #pragma unroll
        for (int kk = 0; kk < 16; ++kk) {
            float4 x0 = *(const float4*)&As[kk][ty * 8];
            float4 x1 = *(const float4*)&As[kk][ty * 8 + 4];
            float4 y  = *(const float4*)&Bs[kk][tx * 4];
            float a[8] = {x0.x, x0.y, x0.z, x0.w, x1.x, x1.y, x1.z, x1.w};
            float bb[4] = {y.x, y.y, y.z, y.w};
            #pragma unroll
            for (int i = 0; i < 8; ++i)
                #pragma unroll
                for (int j = 0; j < 4; ++j)
                    acc[i][j] += a[i] * bb[j];
        }
    }
    #pragma unroll
    for (int i = 0; i < 8; ++i) {
        float4 r;
        r.x = acc[i][0]; r.y = acc[i][1]; r.z = acc[i][2]; r.w = acc[i][3];
        *(float4*)&out[(size_t)(m0 + ty * 8 + i) * 1024 + n0 + tx * 4] = r;
    }
}

// ---------------------------------------------------------------------------
// q, k, lambda projections: N = 16 + 16 + 1 = 33 columns.
// One block = 8 rows of x staged in LDS; 264 dot products.
// ---------------------------------------------------------------------------
__global__ __launch_bounds__(256) void qkl_kernel(const float* __restrict__ X,
    const float* __restrict__ Wq, const float* __restrict__ Wk,
    const float* __restrict__ Wd, const float* __restrict__ bd,
    float* __restrict__ q, float* __restrict__ k, float* __restrict__ lam)
{
    __shared__ float xs[8 * 512];
    const int tid = threadIdx.x;
    const size_t row0 = (size_t)blockIdx.x * 8;
    #pragma unroll
    for (int c = 0; c < 4; ++c) {
        int f = (c * 256 + tid) * 4;
        *(float4*)&xs[f] = *(const float4*)&X[row0 * 512 + f];
    }
    __syncthreads();
    for (int t = tid; t < 264; t += 256) {
        int r = t / 33, c = t - r * 33;
        const float* xr = &xs[r * 512];
        const float* Wp; int ldw;
        if (c < 16)      { Wp = Wq + c;        ldw = 16; }
        else if (c < 32) { Wp = Wk + (c - 16); ldw = 16; }
        else             { Wp = Wd;            ldw = 1;  }
        float s = 0.f;
        for (int kk = 0; kk < 512; ++kk) s += xr[kk] * Wp[(size_t)kk * ldw];
        if (c < 16)      q[(row0 + r) * 16 + c] = s;
        else if (c < 32) k[(row0 + r) * 16 + (c - 16)] = s;
        else             lam[row0 + r] = 1.f / (1.f + expf(-(s + bd[0])));
    }
}

// ---------------------------------------------------------------------------
// Fast-weight scan: one thread per (b,h); F[16] in registers, scan over T.
// Writes pre = xw + read + bias into out0 (RMW), F at t=T-1 into Ffin.
// ---------------------------------------------------------------------------
__global__ __launch_bounds__(256) void scan_kernel(const float* __restrict__ v,
    const float* __restrict__ q, const float* __restrict__ ks,
    const float* __restrict__ lam, const float* __restrict__ bias,
    float* __restrict__ pre, float* __restrict__ Ffin)
{
    const int gid = blockIdx.x * 256 + threadIdx.x;
    const int b = gid >> 10, h = gid & 1023;
    const float* vp = v + (size_t)b * Tc * Hc + h;
    float*       pp = pre + (size_t)b * Tc * Hc + h;
    const float* qp = q + (size_t)b * Tc * Rc;
    const float* kp = ks + (size_t)b * Tc * Rc;
    const float* lp = lam + (size_t)b * Tc;
    const float bh = bias[h];
    float F[16] = {};
    for (int t = 0; t < Tc; t += 2) {
        float ka[16], qa[16], kb[16], qb[16];
        *(float4*)&ka[0]  = *(const float4*)&kp[t * 16];
        *(float4*)&ka[4]  = *(const float4*)&kp[t * 16 + 4];
        *(float4*)&ka[8]  = *(const float4*)&kp[t * 16 + 8];
        *(float4*)&ka[12] = *(const float4*)&kp[t * 16 + 12];
        *(float4*)&qa[0]  = *(const float4*)&qp[t * 16];
        *(float4*)&qa[4]  = *(const float4*)&qp[t * 16 + 4];
        *(float4*)&qa[8]  = *(const float4*)&qp[t * 16 + 8];
        *(float4*)&qa[12] = *(const float4*)&qp[t * 16 + 12];
        *(float4*)&kb[0]  = *(const float4*)&kp[(t + 1) * 16];
        *(float4*)&kb[4]  = *(const float4*)&kp[(t + 1) * 16 + 4];
        *(float4*)&kb[8]  = *(const float4*)&kp[(t + 1) * 16 + 8];
        *(float4*)&kb[12] = *(const float4*)&kp[(t + 1) * 16 + 12];
        *(float4*)&qb[0]  = *(const float4*)&qp[(t + 1) * 16];
        *(float4*)&qb[4]  = *(const float4*)&qp[(t + 1) * 16 + 4];
        *(float4*)&qb[8]  = *(const float4*)&qp[(t + 1) * 16 + 8];
        *(float4*)&qb[12] = *(const float4*)&qp[(t + 1) * 16 + 12];
        const float l0 = lp[t], l1 = lp[t + 1];
        const float v0 = vp[(size_t)t * Hc], v1 = vp[(size_t)(t + 1) * Hc];
        const float w0 = pp[(size_t)t * Hc], w1 = pp[(size_t)(t + 1) * Hc];
        float r0 = 0.f, r1 = 0.f;
        #pragma unroll
        for (int r = 0; r < 16; ++r) { F[r] = l0 * F[r] + v0 * ka[r]; r0 += F[r] * qa[r]; }
        pp[(size_t)t * Hc] = w0 + r0 + bh;
        #pragma unroll
        for (int r = 0; r < 16; ++r) { F[r] = l1 * F[r] + v1 * kb[r]; r1 += F[r] * qb[r]; }
        pp[(size_t)(t + 1) * Hc] = w1 + r1 + bh;
    }
    float* fo = Ffin + ((size_t)b * Hc + h) * 16;
    *(float4*)&fo[0]  = *(float4*)&F[0];
    *(float4*)&fo[4]  = *(float4*)&F[4];
    *(float4*)&fo[8]  = *(float4*)&F[8];
    *(float4*)&fo[12] = *(float4*)&F[12];
}

// ---------------------------------------------------------------------------
// Serial h-recurrence: h_t = tanh(pre_t + h_{t-1} @ Wh).
// 256 WGs = 64 col-slices (16 cols) x 4 batch-groups (4 batches).
// Wh slice lives in REGISTERS (64 f32/thread). Per-group sync via device-
// scope atomic counters; h double-buffered in ws.
// ---------------------------------------------------------------------------
__global__ __launch_bounds__(256) void rec_kernel(const float* __restrict__ Wh,
    float* __restrict__ out0, float* __restrict__ hfin,
    float* __restrict__ hbuf, int* __restrict__ cnt)
{
    __shared__ float hs[4 * 1024];
    __shared__ float red[1024];
    const int tid = threadIdx.x;
    const int w = blockIdx.x;
    const int s = w & 63, g = w >> 6;
    const int c0 = s * 16;
    const int c = tid & 15, part = tid >> 4;   // 16 parts x 64 i's
    float wr[64];
    #pragma unroll
    for (int ii = 0; ii < 64; ++ii)
        wr[ii] = Wh[(size_t)(part * 64 + ii) * 1024 + c0 + c];
    int* mycnt = cnt + g * Tc;
    for (int t = 0; t < Tc; ++t) {
        float* h_rd = hbuf + (t & 1) * (Bc * Hc);
        float* h_wr = hbuf + ((t + 1) & 1) * (Bc * Hc);
        if (t > 0) {
            if (tid == 0) {
                while (__hip_atomic_load(&mycnt[t - 1], __ATOMIC_ACQUIRE,
                                         __HIP_MEMORY_SCOPE_AGENT) < 64)
                    __builtin_amdgcn_s_sleep(1);
            }
            __syncthreads();
            __threadfence();   // acquire side: drop stale cached h
        }
        #pragma unroll
        for (int j = 0; j < 4; ++j) {
            int f = (j * 256 + tid) * 4;
            *(float4*)&hs[f] = *(const float4*)&h_rd[g * 4096 + f];
        }
        __syncthreads();
        float a0 = 0.f, a1 = 0.f, a2 = 0.f, a3 = 0.f;
        #pragma unroll
        for (int i4 = 0; i4 < 16; ++i4) {
            float4 x0 = *(const float4*)&hs[0 * 1024 + part * 64 + i4 * 4];
            float4 x1 = *(const float4*)&hs[1 * 1024 + part * 64 + i4 * 4];
            float4 x2 = *(const float4*)&hs[2 * 1024 + part * 64 + i4 * 4];
            float4 x3 = *(const float4*)&hs[3 * 1024 + part * 64 + i4 * 4];
            const float w0 = wr[i4 * 4 + 0], w1 = wr[i4 * 4 + 1];
            const float w2 = wr[i4 * 4 + 2], w3 = wr[i4 * 4 + 3];
            a0 += x0.x * w0 + x0.y * w1 + x0.z * w2 + x0.w * w3;
            a1 += x1.x * w0 + x1.y * w1 + x1.z * w2 + x1.w * w3;
            a2 += x2.x * w0 + x2.y * w1 + x2.z * w2 + x2.w * w3;
            a3 += x3.x * w0 + x3.y * w1 + x3.z * w2 + x3.w * w3;
        }
        red[part * 64 + c]      = a0;
        red[part * 64 + 16 + c] = a1;
        red[part * 64 + 32 + c] = a2;
        red[part * 64 + 48 + c] = a3;
        __syncthreads();
        if (tid < 64) {
            int bb = tid >> 4, cc = tid & 15;
            float sum = 0.f;
            #pragma unroll
            for (int p = 0; p < 16; ++p) sum += red[p * 64 + bb * 16 + cc];
            int bg = g * 4 + bb;
            size_t oidx = ((size_t)bg * Tc + t) * Hc + c0 + cc;
            float hv = tanhf(out0[oidx] + sum);
            out0[oidx] = hv;
            h_wr[bg * Hc + c0 + cc] = hv;
            if (t == Tc - 1) hfin[bg * Hc + c0 + cc] = hv;
        }
        __threadfence();   // release side: push h/out stores device-wide
        __syncthreads();
        if (tid == 0)
            __hip_atomic_fetch_add(&mycnt[t], 1, __ATOMIC_RELEASE,
                                   __HIP_MEMORY_SCOPE_AGENT);
    }
}

// ---------------------------------------------------------------------------
extern "C" void kernel_launch(void* const* d_in, const int* in_sizes, int n_in,
                              void* d_out, int out_size, void* d_ws, size_t ws_size,
                              hipStream_t stream)
{
    const float* x    = (const float*)d_in[0];
    const float* Wx   = (const float*)d_in[1];
    const float* Wh   = (const float*)d_in[2];
    const float* Wq   = (const float*)d_in[3];
    const float* Wk   = (const float*)d_in[4];
    const float* Wv   = (const float*)d_in[5];
    const float* Wd   = (const float*)d_in[6];
    const float* bias = (const float*)d_in[7];
    const float* bd   = (const float*)d_in[8];

    float* out0 = (float*)d_out;                    // (B,T,H)
    float* hfin = out0 + (size_t)Bc * Tc * Hc;      // (B,H)
    float* Ffin = hfin + (size_t)Bc * Hc;           // (B,H,R)

    float* wsf  = (float*)d_ws;
    float* v    = wsf;                               // B*T*H
    float* q    = v + (size_t)Bc * Tc * Hc;          // B*T*R
    float* k    = q + (size_t)Bc * Tc * Rc;          // B*T*R
    float* lam  = k + (size_t)Bc * Tc * Rc;          // B*T
    float* hbuf = lam + (size_t)Bc * Tc;             // 2 * B*H
    int*   cnt  = (int*)(hbuf + 2 * (size_t)Bc * Hc);// 4 * T

    // zero h ping-pong buffers + sync counters
    hipMemsetAsync(hbuf, 0,
                   2 * (size_t)Bc * Hc * sizeof(float) + 4 * Tc * sizeof(int),
                   stream);

    dim3 gg(256, 16);
    gemm_xw<<<gg, 256, 0, stream>>>(x, Wx, out0);   // xw -> out0
    gemm_xw<<<gg, 256, 0, stream>>>(x, Wv, v);      // v  -> ws
    qkl_kernel<<<4096, 256, 0, stream>>>(x, Wq, Wk, Wd, bd, q, k, lam);
    scan_kernel<<<64, 256, 0, stream>>>(v, q, k, lam, bias, out0, Ffin);
    rec_kernel<<<256, 256, 0, stream>>>(Wh, out0, hfin, hbuf, cnt);
}

// Round 2
// 20121.997 us; speedup vs baseline: 4.4293x; 4.4293x over previous
//
#include <hip/hip_runtime.h>
#include <math.h>

#define Bc 16
#define Tc 2048
#define Dc 512
#define Hc 1024
#define Rc 16

// ---------------------------------------------------------------------------
// GEMM: out[M,1024] = X[M,512] @ W[512,1024], M = 32768.
// BM=128, BN=64, BK=16, 256 threads, 8x4 micro-tile per thread.
// ---------------------------------------------------------------------------
__global__ __launch_bounds__(256) void gemm_xw(const float* __restrict__ X,
                                               const float* __restrict__ W,
                                               float* __restrict__ out)
{
    __shared__ float As[16][128];
    __shared__ float Bs[16][64];
    const int tid = threadIdx.x;
    const int m0 = blockIdx.x * 128;
    const int n0 = blockIdx.y * 64;
    const int tx = tid & 15, ty = tid >> 4;
    const int am = tid >> 2, ak = (tid & 3) * 4;   // A-load: 2 rows (am, am+64), 4 k's
    const int bk = tid >> 4, bn = (tid & 15) * 4;  // B-load: row bk, 4 n's
    float acc[8][4] = {};
    for (int k0 = 0; k0 < 512; k0 += 16) {
        if (k0) __syncthreads();
        float4 a0 = *(const float4*)&X[(size_t)(m0 + am) * 512 + k0 + ak];
        float4 a1 = *(const float4*)&X[(size_t)(m0 + am + 64) * 512 + k0 + ak];
        float4 bv = *(const float4*)&W[(size_t)(k0 + bk) * 1024 + n0 + bn];
        As[ak + 0][am] = a0.x; As[ak + 1][am] = a0.y;
        As[ak + 2][am] = a0.z; As[ak + 3][am] = a0.w;
        As[ak + 0][am + 64] = a1.x; As[ak + 1][am + 64] = a1.y;
        As[ak + 2][am + 64] = a1.z; As[ak + 3][am + 64] = a1.w;
        *(float4*)&Bs[bk][bn] = bv;
        __syncthreads();
        #pragma unroll
        for (int kk = 0; kk < 16; ++kk) {
            float4 x0 = *(const float4*)&As[kk][ty * 8];
            float4 x1 = *(const float4*)&As[kk][ty * 8 + 4];
            float4 y  = *(const float4*)&Bs[kk][tx * 4];
            float a[8] = {x0.x, x0.y, x0.z, x0.w, x1.x, x1.y, x1.z, x1.w};
            float bb[4] = {y.x, y.y, y.z, y.w};
            #pragma unroll
            for (int i = 0; i < 8; ++i)
                #pragma unroll
                for (int j = 0; j < 4; ++j)
                    acc[i][j] += a[i] * bb[j];
        }
    }
    #pragma unroll
    for (int i = 0; i < 8; ++i) {
        float4 r;
        r.x = acc[i][0]; r.y = acc[i][1]; r.z = acc[i][2]; r.w = acc[i][3];
        *(float4*)&out[(size_t)(m0 + ty * 8 + i) * 1024 + n0 + tx * 4] = r;
    }
}

// ---------------------------------------------------------------------------
// q, k, lambda projections: N = 16 + 16 + 1 = 33 columns.
// ---------------------------------------------------------------------------
__global__ __launch_bounds__(256) void qkl_kernel(const float* __restrict__ X,
    const float* __restrict__ Wq, const float* __restrict__ Wk,
    const float* __restrict__ Wd, const float* __restrict__ bd,
    float* __restrict__ q, float* __restrict__ k, float* __restrict__ lam)
{
    __shared__ float xs[8 * 512];
    const int tid = threadIdx.x;
    const size_t row0 = (size_t)blockIdx.x * 8;
    #pragma unroll
    for (int c = 0; c < 4; ++c) {
        int f = (c * 256 + tid) * 4;
        *(float4*)&xs[f] = *(const float4*)&X[row0 * 512 + f];
    }
    __syncthreads();
    for (int t = tid; t < 264; t += 256) {
        int r = t / 33, c = t - r * 33;
        const float* xr = &xs[r * 512];
        const float* Wp; int ldw;
        if (c < 16)      { Wp = Wq + c;        ldw = 16; }
        else if (c < 32) { Wp = Wk + (c - 16); ldw = 16; }
        else             { Wp = Wd;            ldw = 1;  }
        float s = 0.f;
        for (int kk = 0; kk < 512; ++kk) s += xr[kk] * Wp[(size_t)kk * ldw];
        if (c < 16)      q[(row0 + r) * 16 + c] = s;
        else if (c < 32) k[(row0 + r) * 16 + (c - 16)] = s;
        else             lam[row0 + r] = 1.f / (1.f + expf(-(s + bd[0])));
    }
}

// ---------------------------------------------------------------------------
// Fast-weight scan: one thread per (b,h); F[16] in registers, scan over T.
// ---------------------------------------------------------------------------
__global__ __launch_bounds__(256) void scan_kernel(const float* __restrict__ v,
    const float* __restrict__ q, const float* __restrict__ ks,
    const float* __restrict__ lam, const float* __restrict__ bias,
    float* __restrict__ pre, float* __restrict__ Ffin)
{
    const int gid = blockIdx.x * 256 + threadIdx.x;
    const int b = gid >> 10, h = gid & 1023;
    const float* vp = v + (size_t)b * Tc * Hc + h;
    float*       pp = pre + (size_t)b * Tc * Hc + h;
    const float* qp = q + (size_t)b * Tc * Rc;
    const float* kp = ks + (size_t)b * Tc * Rc;
    const float* lp = lam + (size_t)b * Tc;
    const float bh = bias[h];
    float F[16] = {};
    for (int t = 0; t < Tc; t += 2) {
        float ka[16], qa[16], kb[16], qb[16];
        *(float4*)&ka[0]  = *(const float4*)&kp[t * 16];
        *(float4*)&ka[4]  = *(const float4*)&kp[t * 16 + 4];
        *(float4*)&ka[8]  = *(const float4*)&kp[t * 16 + 8];
        *(float4*)&ka[12] = *(const float4*)&kp[t * 16 + 12];
        *(float4*)&qa[0]  = *(const float4*)&qp[t * 16];
        *(float4*)&qa[4]  = *(const float4*)&qp[t * 16 + 4];
        *(float4*)&qa[8]  = *(const float4*)&qp[t * 16 + 8];
        *(float4*)&qa[12] = *(const float4*)&qp[t * 16 + 12];
        *(float4*)&kb[0]  = *(const float4*)&kp[(t + 1) * 16];
        *(float4*)&kb[4]  = *(const float4*)&kp[(t + 1) * 16 + 4];
        *(float4*)&kb[8]  = *(const float4*)&kp[(t + 1) * 16 + 8];
        *(float4*)&kb[12] = *(const float4*)&kp[(t + 1) * 16 + 12];
        *(float4*)&qb[0]  = *(const float4*)&qp[(t + 1) * 16];
        *(float4*)&qb[4]  = *(const float4*)&qp[(t + 1) * 16 + 4];
        *(float4*)&qb[8]  = *(const float4*)&qp[(t + 1) * 16 + 8];
        *(float4*)&qb[12] = *(const float4*)&qp[(t + 1) * 16 + 12];
        const float l0 = lp[t], l1 = lp[t + 1];
        const float v0 = vp[(size_t)t * Hc], v1 = vp[(size_t)(t + 1) * Hc];
        const float w0 = pp[(size_t)t * Hc], w1 = pp[(size_t)(t + 1) * Hc];
        float r0 = 0.f, r1 = 0.f;
        #pragma unroll
        for (int r = 0; r < 16; ++r) { F[r] = l0 * F[r] + v0 * ka[r]; r0 += F[r] * qa[r]; }
        pp[(size_t)t * Hc] = w0 + r0 + bh;
        #pragma unroll
        for (int r = 0; r < 16; ++r) { F[r] = l1 * F[r] + v1 * kb[r]; r1 += F[r] * qb[r]; }
        pp[(size_t)(t + 1) * Hc] = w1 + r1 + bh;
    }
    float* fo = Ffin + ((size_t)b * Hc + h) * 16;
    *(float4*)&fo[0]  = *(float4*)&F[0];
    *(float4*)&fo[4]  = *(float4*)&F[4];
    *(float4*)&fo[8]  = *(float4*)&F[8];
    *(float4*)&fo[12] = *(float4*)&F[12];
}

// ---------------------------------------------------------------------------
// Serial h-recurrence: h_t = tanh(pre_t + h_{t-1} @ Wh).
// 256 WGs = 64 col-slices x 4 batch-groups. Wh slice in REGISTERS
// (launch_bounds(256,1) so the 64 f32/thread do NOT spill).
// Cross-WG h exchange via sc0 sc1 (coherent-point) loads/stores; signal via
// per-WG progress words (coalesced 64-slot poll, no atomic contention, no
// fences -> no L2 invalidation).
// ---------------------------------------------------------------------------
__global__ __launch_bounds__(256, 1) void rec_kernel(const float* __restrict__ Wh,
    float* __restrict__ out0, float* __restrict__ hfin,
    float* __restrict__ hbuf, int* __restrict__ progress)
{
    __shared__ float hs[4 * 1024];
    __shared__ float red[16 * 65];
    const int tid = threadIdx.x;
    const int w = blockIdx.x;
    const int sl = w & 63, g = w >> 6;
    const int c0 = sl * 16;
    const int c = tid & 15, part = tid >> 4;   // 16 k-parts x 16 cols
    float wr[64];
    #pragma unroll
    for (int ii = 0; ii < 64; ++ii)
        wr[ii] = Wh[(size_t)(part * 64 + ii) * 1024 + c0 + c];
    int* prog = progress + g * 64;
    const int bb = tid >> 4, cc = tid & 15;    // epilogue roles (tid < 64)
    const int bg = g * 4 + bb;

    for (int t = 0; t < Tc; ++t) {
        float* h_rd = hbuf + (t & 1) * (Bc * Hc) + g * 4096;
        float* h_wr = hbuf + ((t + 1) & 1) * (Bc * Hc) + g * 4096;
        // Prefetch pre-activation (independent of h) before the spin.
        float pre_t = 0.f;
        size_t oidx = 0;
        if (tid < 64) {
            oidx = ((size_t)bg * Tc + t) * Hc + c0 + cc;
            pre_t = out0[oidx];
        }
        if (t > 0) {
            if (tid < 64) {
                while (1) {
                    int pv = __hip_atomic_load(&prog[tid], __ATOMIC_RELAXED,
                                               __HIP_MEMORY_SCOPE_AGENT);
                    if (__all(pv >= t)) break;
                    __builtin_amdgcn_s_sleep(1);
                }
            }
            __syncthreads();                   // barrier A
            const float* p0 = h_rd + tid * 4;
            const float* p1 = p0 + 1024;
            const float* p2 = p0 + 2048;
            const float* p3 = p0 + 3072;
            float4 r0, r1, r2, r3;
            asm volatile(
                "global_load_dwordx4 %0, %4, off sc0 sc1\n\t"
                "global_load_dwordx4 %1, %5, off sc0 sc1\n\t"
                "global_load_dwordx4 %2, %6, off sc0 sc1\n\t"
                "global_load_dwordx4 %3, %7, off sc0 sc1\n\t"
                "s_waitcnt vmcnt(0)"
                : "=&v"(r0), "=&v"(r1), "=&v"(r2), "=&v"(r3)
                : "v"(p0), "v"(p1), "v"(p2), "v"(p3)
                : "memory");
            *(float4*)&hs[0 * 1024 + tid * 4] = r0;
            *(float4*)&hs[1 * 1024 + tid * 4] = r1;
            *(float4*)&hs[2 * 1024 + tid * 4] = r2;
            *(float4*)&hs[3 * 1024 + tid * 4] = r3;
        } else {
            float4 z = {0.f, 0.f, 0.f, 0.f};
            *(float4*)&hs[0 * 1024 + tid * 4] = z;
            *(float4*)&hs[1 * 1024 + tid * 4] = z;
            *(float4*)&hs[2 * 1024 + tid * 4] = z;
            *(float4*)&hs[3 * 1024 + tid * 4] = z;
        }
        __syncthreads();                       // barrier B
        float a0 = 0.f, a1 = 0.f, a2 = 0.f, a3 = 0.f;
        #pragma unroll
        for (int u = 0; u < 16; ++u) {
            const int i4 = (u + part * 4) & 15;    // bank stagger across parts
            float4 x0 = *(const float4*)&hs[0 * 1024 + part * 64 + i4 * 4];
            float4 x1 = *(const float4*)&hs[1 * 1024 + part * 64 + i4 * 4];
            float4 x2 = *(const float4*)&hs[2 * 1024 + part * 64 + i4 * 4];
            float4 x3 = *(const float4*)&hs[3 * 1024 + part * 64 + i4 * 4];
            const float w0 = wr[i4 * 4 + 0], w1 = wr[i4 * 4 + 1];
            const float w2 = wr[i4 * 4 + 2], w3 = wr[i4 * 4 + 3];
            a0 += x0.x * w0 + x0.y * w1 + x0.z * w2 + x0.w * w3;
            a1 += x1.x * w0 + x1.y * w1 + x1.z * w2 + x1.w * w3;
            a2 += x2.x * w0 + x2.y * w1 + x2.z * w2 + x2.w * w3;
            a3 += x3.x * w0 + x3.y * w1 + x3.z * w2 + x3.w * w3;
        }
        red[part * 65 + 0  + c] = a0;
        red[part * 65 + 16 + c] = a1;
        red[part * 65 + 32 + c] = a2;
        red[part * 65 + 48 + c] = a3;
        __syncthreads();                       // barrier C
        if (tid < 64) {
            float sum = 0.f;
            #pragma unroll
            for (int p = 0; p < 16; ++p) sum += red[p * 65 + tid];
            float hv = tanhf(pre_t + sum);
            out0[oidx] = hv;                   // cached store (final output)
            if (t == Tc - 1) hfin[(size_t)bg * Hc + c0 + cc] = hv;
            float* hp = h_wr + bb * 1024 + c0 + cc;
            asm volatile(
                "global_store_dword %0, %1, off sc0 sc1\n\t"
                "s_waitcnt vmcnt(0)"
                :: "v"(hp), "v"(hv) : "memory");
            if (tid == 0)
                __hip_atomic_store(&prog[sl], t + 1, __ATOMIC_RELAXED,
                                   __HIP_MEMORY_SCOPE_AGENT);
        }
    }
}

// ---------------------------------------------------------------------------
extern "C" void kernel_launch(void* const* d_in, const int* in_sizes, int n_in,
                              void* d_out, int out_size, void* d_ws, size_t ws_size,
                              hipStream_t stream)
{
    const float* x    = (const float*)d_in[0];
    const float* Wx   = (const float*)d_in[1];
    const float* Wh   = (const float*)d_in[2];
    const float* Wq   = (const float*)d_in[3];
    const float* Wk   = (const float*)d_in[4];
    const float* Wv   = (const float*)d_in[5];
    const float* Wd   = (const float*)d_in[6];
    const float* bias = (const float*)d_in[7];
    const float* bd   = (const float*)d_in[8];

    float* out0 = (float*)d_out;                    // (B,T,H)
    float* hfin = out0 + (size_t)Bc * Tc * Hc;      // (B,H)
    float* Ffin = hfin + (size_t)Bc * Hc;           // (B,H,R)

    float* wsf  = (float*)d_ws;
    float* v    = wsf;                               // B*T*H
    float* q    = v + (size_t)Bc * Tc * Hc;          // B*T*R
    float* k    = q + (size_t)Bc * Tc * Rc;          // B*T*R
    float* lam  = k + (size_t)Bc * Tc * Rc;          // B*T
    float* hbuf = lam + (size_t)Bc * Tc;             // 2 * B*H ping-pong
    int*   prg  = (int*)(hbuf + 2 * (size_t)Bc * Hc);// 4 groups * 64 slices

    hipMemsetAsync(prg, 0, 256 * sizeof(int), stream);

    dim3 gg(256, 16);
    gemm_xw<<<gg, 256, 0, stream>>>(x, Wx, out0);   // xw -> out0
    gemm_xw<<<gg, 256, 0, stream>>>(x, Wv, v);      // v  -> ws
    qkl_kernel<<<4096, 256, 0, stream>>>(x, Wq, Wk, Wd, bd, q, k, lam);
    scan_kernel<<<64, 256, 0, stream>>>(v, q, k, lam, bias, out0, Ffin);
    rec_kernel<<<256, 256, 0, stream>>>(Wh, out0, hfin, hbuf, prg);
}

// Round 3
// 12513.297 us; speedup vs baseline: 7.1226x; 1.6080x over previous
//
#include <hip/hip_runtime.h>
#include <math.h>

#define Bc 16
#define Tc 2048
#define Dc 512
#define Hc 1024
#define Rc 16

// ---------------------------------------------------------------------------
// GEMM: out[M,1024] = X[M,512] @ W[512,1024], M = 32768.
// BM=128, BN=64, BK=16, 256 threads, 8x4 micro-tile per thread.
// ---------------------------------------------------------------------------
__global__ __launch_bounds__(256) void gemm_xw(const float* __restrict__ X,
                                               const float* __restrict__ W,
                                               float* __restrict__ out)
{
    __shared__ float As[16][128];
    __shared__ float Bs[16][64];
    const int tid = threadIdx.x;
    const int m0 = blockIdx.x * 128;
    const int n0 = blockIdx.y * 64;
    const int tx = tid & 15, ty = tid >> 4;
    const int am = tid >> 2, ak = (tid & 3) * 4;   // A-load: 2 rows (am, am+64), 4 k's
    const int bk = tid >> 4, bn = (tid & 15) * 4;  // B-load: row bk, 4 n's
    float acc[8][4] = {};
    for (int k0 = 0; k0 < 512; k0 += 16) {
        if (k0) __syncthreads();
        float4 a0 = *(const float4*)&X[(size_t)(m0 + am) * 512 + k0 + ak];
        float4 a1 = *(const float4*)&X[(size_t)(m0 + am + 64) * 512 + k0 + ak];
        float4 bv = *(const float4*)&W[(size_t)(k0 + bk) * 1024 + n0 + bn];
        As[ak + 0][am] = a0.x; As[ak + 1][am] = a0.y;
        As[ak + 2][am] = a0.z; As[ak + 3][am] = a0.w;
        As[ak + 0][am + 64] = a1.x; As[ak + 1][am + 64] = a1.y;
        As[ak + 2][am + 64] = a1.z; As[ak + 3][am + 64] = a1.w;
        *(float4*)&Bs[bk][bn] = bv;
        __syncthreads();
        #pragma unroll
        for (int kk = 0; kk < 16; ++kk) {
            float4 x0 = *(const float4*)&As[kk][ty * 8];
            float4 x1 = *(const float4*)&As[kk][ty * 8 + 4];
            float4 y  = *(const float4*)&Bs[kk][tx * 4];
            float a[8] = {x0.x, x0.y, x0.z, x0.w, x1.x, x1.y, x1.z, x1.w};
            float bb[4] = {y.x, y.y, y.z, y.w};
            #pragma unroll
            for (int i = 0; i < 8; ++i)
                #pragma unroll
                for (int j = 0; j < 4; ++j)
                    acc[i][j] += a[i] * bb[j];
        }
    }
    #pragma unroll
    for (int i = 0; i < 8; ++i) {
        float4 r;
        r.x = acc[i][0]; r.y = acc[i][1]; r.z = acc[i][2]; r.w = acc[i][3];
        *(float4*)&out[(size_t)(m0 + ty * 8 + i) * 1024 + n0 + tx * 4] = r;
    }
}

// ---------------------------------------------------------------------------
// q, k, lambda projections: N = 16 + 16 + 1 = 33 columns.
// ---------------------------------------------------------------------------
__global__ __launch_bounds__(256) void qkl_kernel(const float* __restrict__ X,
    const float* __restrict__ Wq, const float* __restrict__ Wk,
    const float* __restrict__ Wd, const float* __restrict__ bd,
    float* __restrict__ q, float* __restrict__ k, float* __restrict__ lam)
{
    __shared__ float xs[8 * 512];
    const int tid = threadIdx.x;
    const size_t row0 = (size_t)blockIdx.x * 8;
    #pragma unroll
    for (int c = 0; c < 4; ++c) {
        int f = (c * 256 + tid) * 4;
        *(float4*)&xs[f] = *(const float4*)&X[row0 * 512 + f];
    }
    __syncthreads();
    for (int t = tid; t < 264; t += 256) {
        int r = t / 33, c = t - r * 33;
        const float* xr = &xs[r * 512];
        const float* Wp; int ldw;
        if (c < 16)      { Wp = Wq + c;        ldw = 16; }
        else if (c < 32) { Wp = Wk + (c - 16); ldw = 16; }
        else             { Wp = Wd;            ldw = 1;  }
        float s = 0.f;
        for (int kk = 0; kk < 512; ++kk) s += xr[kk] * Wp[(size_t)kk * ldw];
        if (c < 16)      q[(row0 + r) * 16 + c] = s;
        else if (c < 32) k[(row0 + r) * 16 + (c - 16)] = s;
        else             lam[row0 + r] = 1.f / (1.f + expf(-(s + bd[0])));
    }
}

// ---------------------------------------------------------------------------
// Fast-weight scan: one thread per (b,h); F[16] in registers, scan over T.
// ---------------------------------------------------------------------------
__global__ __launch_bounds__(256) void scan_kernel(const float* __restrict__ v,
    const float* __restrict__ q, const float* __restrict__ ks,
    const float* __restrict__ lam, const float* __restrict__ bias,
    float* __restrict__ pre, float* __restrict__ Ffin)
{
    const int gid = blockIdx.x * 256 + threadIdx.x;
    const int b = gid >> 10, h = gid & 1023;
    const float* vp = v + (size_t)b * Tc * Hc + h;
    float*       pp = pre + (size_t)b * Tc * Hc + h;
    const float* qp = q + (size_t)b * Tc * Rc;
    const float* kp = ks + (size_t)b * Tc * Rc;
    const float* lp = lam + (size_t)b * Tc;
    const float bh = bias[h];
    float F[16] = {};
    for (int t = 0; t < Tc; t += 2) {
        float ka[16], qa[16], kb[16], qb[16];
        *(float4*)&ka[0]  = *(const float4*)&kp[t * 16];
        *(float4*)&ka[4]  = *(const float4*)&kp[t * 16 + 4];
        *(float4*)&ka[8]  = *(const float4*)&kp[t * 16 + 8];
        *(float4*)&ka[12] = *(const float4*)&kp[t * 16 + 12];
        *(float4*)&qa[0]  = *(const float4*)&qp[t * 16];
        *(float4*)&qa[4]  = *(const float4*)&qp[t * 16 + 4];
        *(float4*)&qa[8]  = *(const float4*)&qp[t * 16 + 8];
        *(float4*)&qa[12] = *(const float4*)&qp[t * 16 + 12];
        *(float4*)&kb[0]  = *(const float4*)&kp[(t + 1) * 16];
        *(float4*)&kb[4]  = *(const float4*)&kp[(t + 1) * 16 + 4];
        *(float4*)&kb[8]  = *(const float4*)&kp[(t + 1) * 16 + 8];
        *(float4*)&kb[12] = *(const float4*)&kp[(t + 1) * 16 + 12];
        *(float4*)&qb[0]  = *(const float4*)&qp[(t + 1) * 16];
        *(float4*)&qb[4]  = *(const float4*)&qp[(t + 1) * 16 + 4];
        *(float4*)&qb[8]  = *(const float4*)&qp[(t + 1) * 16 + 8];
        *(float4*)&qb[12] = *(const float4*)&qp[(t + 1) * 16 + 12];
        const float l0 = lp[t], l1 = lp[t + 1];
        const float v0 = vp[(size_t)t * Hc], v1 = vp[(size_t)(t + 1) * Hc];
        const float w0 = pp[(size_t)t * Hc], w1 = pp[(size_t)(t + 1) * Hc];
        float r0 = 0.f, r1 = 0.f;
        #pragma unroll
        for (int r = 0; r < 16; ++r) { F[r] = l0 * F[r] + v0 * ka[r]; r0 += F[r] * qa[r]; }
        pp[(size_t)t * Hc] = w0 + r0 + bh;
        #pragma unroll
        for (int r = 0; r < 16; ++r) { F[r] = l1 * F[r] + v1 * kb[r]; r1 += F[r] * qb[r]; }
        pp[(size_t)(t + 1) * Hc] = w1 + r1 + bh;
    }
    float* fo = Ffin + ((size_t)b * Hc + h) * 16;
    *(float4*)&fo[0]  = *(float4*)&F[0];
    *(float4*)&fo[4]  = *(float4*)&F[4];
    *(float4*)&fo[8]  = *(float4*)&F[8];
    *(float4*)&fo[12] = *(float4*)&F[12];
}

// ---------------------------------------------------------------------------
// Serial h-recurrence: h_t = tanh(pre_t + h_{t-1} @ Wh).
// 256 WGs = 64 col-slices x 4 batch-groups. Wh slice in REGISTERS.
// KEY FIX vs R2: weight array is stored PRE-PERMUTED so that every wr[]
// index in the compute loop is compile-time constant (runtime-indexed
// ext arrays go to scratch -> was VGPR=44 + 16 MB/step spill traffic).
// The LDS-read stagger (bank-conflict fix) is preserved on the hs side.
// ---------------------------------------------------------------------------
__global__ __launch_bounds__(256, 1) void rec_kernel(const float* __restrict__ Wh,
    float* __restrict__ out0, float* __restrict__ hfin,
    float* __restrict__ hbuf, int* __restrict__ progress)
{
    __shared__ float hs[4 * 1024];
    __shared__ float red[16 * 65];
    const int tid = threadIdx.x;
    const int w = blockIdx.x;
    const int sl = w & 63, g = w >> 6;
    const int c0 = sl * 16;
    const int c = tid & 15, part = tid >> 4;   // 16 k-parts x 16 cols
    // Pre-permuted weight load: wr[u*4+j] corresponds to row (part*64 +
    // ((u+part*4)&15)*4 + j) -- matches the staggered hs read in the u-loop.
    float wr[64];
    #pragma unroll
    for (int u = 0; u < 16; ++u) {
        const int i4 = (u + part * 4) & 15;
        #pragma unroll
        for (int j = 0; j < 4; ++j)
            wr[u * 4 + j] = Wh[(size_t)(part * 64 + i4 * 4 + j) * 1024 + c0 + c];
    }
    int* prog = progress + g * 64;
    const int bb = tid >> 4, cc = tid & 15;    // epilogue roles (tid < 64)
    const int bg = g * 4 + bb;

    for (int t = 0; t < Tc; ++t) {
        float* h_rd = hbuf + (t & 1) * (Bc * Hc) + g * 4096;
        float* h_wr = hbuf + ((t + 1) & 1) * (Bc * Hc) + g * 4096;
        // Prefetch pre-activation (independent of h) before the spin.
        float pre_t = 0.f;
        size_t oidx = 0;
        if (tid < 64) {
            oidx = ((size_t)bg * Tc + t) * Hc + c0 + cc;
            pre_t = out0[oidx];
        }
        if (t > 0) {
            if (tid < 64) {
                while (1) {
                    int pv = __hip_atomic_load(&prog[tid], __ATOMIC_RELAXED,
                                               __HIP_MEMORY_SCOPE_AGENT);
                    if (__all(pv >= t)) break;
                    __builtin_amdgcn_s_sleep(1);
                }
            }
            __syncthreads();                   // barrier A
            const float* p0 = h_rd + tid * 4;
            const float* p1 = p0 + 1024;
            const float* p2 = p0 + 2048;
            const float* p3 = p0 + 3072;
            float4 r0, r1, r2, r3;
            asm volatile(
                "global_load_dwordx4 %0, %4, off sc0 sc1\n\t"
                "global_load_dwordx4 %1, %5, off sc0 sc1\n\t"
                "global_load_dwordx4 %2, %6, off sc0 sc1\n\t"
                "global_load_dwordx4 %3, %7, off sc0 sc1\n\t"
                "s_waitcnt vmcnt(0)"
                : "=&v"(r0), "=&v"(r1), "=&v"(r2), "=&v"(r3)
                : "v"(p0), "v"(p1), "v"(p2), "v"(p3)
                : "memory");
            *(float4*)&hs[0 * 1024 + tid * 4] = r0;
            *(float4*)&hs[1 * 1024 + tid * 4] = r1;
            *(float4*)&hs[2 * 1024 + tid * 4] = r2;
            *(float4*)&hs[3 * 1024 + tid * 4] = r3;
        } else {
            float4 z = {0.f, 0.f, 0.f, 0.f};
            *(float4*)&hs[0 * 1024 + tid * 4] = z;
            *(float4*)&hs[1 * 1024 + tid * 4] = z;
            *(float4*)&hs[2 * 1024 + tid * 4] = z;
            *(float4*)&hs[3 * 1024 + tid * 4] = z;
        }
        __syncthreads();                       // barrier B
        float a0 = 0.f, a1 = 0.f, a2 = 0.f, a3 = 0.f;
        #pragma unroll
        for (int u = 0; u < 16; ++u) {
            const int i4 = (u + part * 4) & 15;    // bank stagger across parts
            float4 x0 = *(const float4*)&hs[0 * 1024 + part * 64 + i4 * 4];
            float4 x1 = *(const float4*)&hs[1 * 1024 + part * 64 + i4 * 4];
            float4 x2 = *(const float4*)&hs[2 * 1024 + part * 64 + i4 * 4];
            float4 x3 = *(const float4*)&hs[3 * 1024 + part * 64 + i4 * 4];
            const float w0 = wr[u * 4 + 0], w1 = wr[u * 4 + 1];
            const float w2 = wr[u * 4 + 2], w3 = wr[u * 4 + 3];
            a0 += x0.x * w0 + x0.y * w1 + x0.z * w2 + x0.w * w3;
            a1 += x1.x * w0 + x1.y * w1 + x1.z * w2 + x1.w * w3;
            a2 += x2.x * w0 + x2.y * w1 + x2.z * w2 + x2.w * w3;
            a3 += x3.x * w0 + x3.y * w1 + x3.z * w2 + x3.w * w3;
        }
        red[part * 65 + 0  + c] = a0;
        red[part * 65 + 16 + c] = a1;
        red[part * 65 + 32 + c] = a2;
        red[part * 65 + 48 + c] = a3;
        __syncthreads();                       // barrier C
        if (tid < 64) {
            float sum = 0.f;
            #pragma unroll
            for (int p = 0; p < 16; ++p) sum += red[p * 65 + tid];
            float hv = tanhf(pre_t + sum);
            out0[oidx] = hv;                   // cached store (final output)
            if (t == Tc - 1) hfin[(size_t)bg * Hc + c0 + cc] = hv;
            float* hp = h_wr + bb * 1024 + c0 + cc;
            asm volatile(
                "global_store_dword %0, %1, off sc0 sc1\n\t"
                "s_waitcnt vmcnt(0)"
                :: "v"(hp), "v"(hv) : "memory");
            if (tid == 0)
                __hip_atomic_store(&prog[sl], t + 1, __ATOMIC_RELAXED,
                                   __HIP_MEMORY_SCOPE_AGENT);
        }
    }
}

// ---------------------------------------------------------------------------
extern "C" void kernel_launch(void* const* d_in, const int* in_sizes, int n_in,
                              void* d_out, int out_size, void* d_ws, size_t ws_size,
                              hipStream_t stream)
{
    const float* x    = (const float*)d_in[0];
    const float* Wx   = (const float*)d_in[1];
    const float* Wh   = (const float*)d_in[2];
    const float* Wq   = (const float*)d_in[3];
    const float* Wk   = (const float*)d_in[4];
    const float* Wv   = (const float*)d_in[5];
    const float* Wd   = (const float*)d_in[6];
    const float* bias = (const float*)d_in[7];
    const float* bd   = (const float*)d_in[8];

    float* out0 = (float*)d_out;                    // (B,T,H)
    float* hfin = out0 + (size_t)Bc * Tc * Hc;      // (B,H)
    float* Ffin = hfin + (size_t)Bc * Hc;           // (B,H,R)

    float* wsf  = (float*)d_ws;
    float* v    = wsf;                               // B*T*H
    float* q    = v + (size_t)Bc * Tc * Hc;          // B*T*R
    float* k    = q + (size_t)Bc * Tc * Rc;          // B*T*R
    float* lam  = k + (size_t)Bc * Tc * Rc;          // B*T
    float* hbuf = lam + (size_t)Bc * Tc;             // 2 * B*H ping-pong
    int*   prg  = (int*)(hbuf + 2 * (size_t)Bc * Hc);// 4 groups * 64 slices

    hipMemsetAsync(prg, 0, 256 * sizeof(int), stream);

    dim3 gg(256, 16);
    gemm_xw<<<gg, 256, 0, stream>>>(x, Wx, out0);   // xw -> out0
    gemm_xw<<<gg, 256, 0, stream>>>(x, Wv, v);      // v  -> ws
    qkl_kernel<<<4096, 256, 0, stream>>>(x, Wq, Wk, Wd, bd, q, k, lam);
    scan_kernel<<<64, 256, 0, stream>>>(v, q, k, lam, bias, out0, Ffin);
    rec_kernel<<<256, 256, 0, stream>>>(Wh, out0, hfin, hbuf, prg);
}

// Round 4
// 10391.040 us; speedup vs baseline: 8.5773x; 1.2042x over previous
//
#include <hip/hip_runtime.h>
#include <math.h>

#define Bc 16
#define Tc 2048
#define Dc 512
#define Hc 1024
#define Rc 16

// ---------------------------------------------------------------------------
// GEMM: out[M,1024] = X[M,512] @ W[512,1024], M = 32768.
// BM=128, BN=64, BK=16, 256 threads, 8x4 micro-tile per thread.
// ---------------------------------------------------------------------------
__global__ __launch_bounds__(256) void gemm_xw(const float* __restrict__ X,
                                               const float* __restrict__ W,
                                               float* __restrict__ out)
{
    __shared__ float As[16][128];
    __shared__ float Bs[16][64];
    const int tid = threadIdx.x;
    const int m0 = blockIdx.x * 128;
    const int n0 = blockIdx.y * 64;
    const int tx = tid & 15, ty = tid >> 4;
    const int am = tid >> 2, ak = (tid & 3) * 4;   // A-load: 2 rows (am, am+64), 4 k's
    const int bk = tid >> 4, bn = (tid & 15) * 4;  // B-load: row bk, 4 n's
    float acc[8][4] = {};
    for (int k0 = 0; k0 < 512; k0 += 16) {
        if (k0) __syncthreads();
        float4 a0 = *(const float4*)&X[(size_t)(m0 + am) * 512 + k0 + ak];
        float4 a1 = *(const float4*)&X[(size_t)(m0 + am + 64) * 512 + k0 + ak];
        float4 bv = *(const float4*)&W[(size_t)(k0 + bk) * 1024 + n0 + bn];
        As[ak + 0][am] = a0.x; As[ak + 1][am] = a0.y;
        As[ak + 2][am] = a0.z; As[ak + 3][am] = a0.w;
        As[ak + 0][am + 64] = a1.x; As[ak + 1][am + 64] = a1.y;
        As[ak + 2][am + 64] = a1.z; As[ak + 3][am + 64] = a1.w;
        *(float4*)&Bs[bk][bn] = bv;
        __syncthreads();
        #pragma unroll
        for (int kk = 0; kk < 16; ++kk) {
            float4 x0 = *(const float4*)&As[kk][ty * 8];
            float4 x1 = *(const float4*)&As[kk][ty * 8 + 4];
            float4 y  = *(const float4*)&Bs[kk][tx * 4];
            float a[8] = {x0.x, x0.y, x0.z, x0.w, x1.x, x1.y, x1.z, x1.w};
            float bb[4] = {y.x, y.y, y.z, y.w};
            #pragma unroll
            for (int i = 0; i < 8; ++i)
                #pragma unroll
                for (int j = 0; j < 4; ++j)
                    acc[i][j] += a[i] * bb[j];
        }
    }
    #pragma unroll
    for (int i = 0; i < 8; ++i) {
        float4 r;
        r.x = acc[i][0]; r.y = acc[i][1]; r.z = acc[i][2]; r.w = acc[i][3];
        *(float4*)&out[(size_t)(m0 + ty * 8 + i) * 1024 + n0 + tx * 4] = r;
    }
}

// ---------------------------------------------------------------------------
// q, k, lambda projections: N = 16 + 16 + 1 = 33 columns.
// ---------------------------------------------------------------------------
__global__ __launch_bounds__(256) void qkl_kernel(const float* __restrict__ X,
    const float* __restrict__ Wq, const float* __restrict__ Wk,
    const float* __restrict__ Wd, const float* __restrict__ bd,
    float* __restrict__ q, float* __restrict__ k, float* __restrict__ lam)
{
    __shared__ float xs[8 * 512];
    const int tid = threadIdx.x;
    const size_t row0 = (size_t)blockIdx.x * 8;
    #pragma unroll
    for (int c = 0; c < 4; ++c) {
        int f = (c * 256 + tid) * 4;
        *(float4*)&xs[f] = *(const float4*)&X[row0 * 512 + f];
    }
    __syncthreads();
    for (int t = tid; t < 264; t += 256) {
        int r = t / 33, c = t - r * 33;
        const float* xr = &xs[r * 512];
        const float* Wp; int ldw;
        if (c < 16)      { Wp = Wq + c;        ldw = 16; }
        else if (c < 32) { Wp = Wk + (c - 16); ldw = 16; }
        else             { Wp = Wd;            ldw = 1;  }
        float s = 0.f;
        for (int kk = 0; kk < 512; ++kk) s += xr[kk] * Wp[(size_t)kk * ldw];
        if (c < 16)      q[(row0 + r) * 16 + c] = s;
        else if (c < 32) k[(row0 + r) * 16 + (c - 16)] = s;
        else             lam[row0 + r] = 1.f / (1.f + expf(-(s + bd[0])));
    }
}

// ---------------------------------------------------------------------------
// Fast-weight scan: one thread per (b,h); F[16] in registers, scan over T.
// ---------------------------------------------------------------------------
__global__ __launch_bounds__(256) void scan_kernel(const float* __restrict__ v,
    const float* __restrict__ q, const float* __restrict__ ks,
    const float* __restrict__ lam, const float* __restrict__ bias,
    float* __restrict__ pre, float* __restrict__ Ffin)
{
    const int gid = blockIdx.x * 256 + threadIdx.x;
    const int b = gid >> 10, h = gid & 1023;
    const float* vp = v + (size_t)b * Tc * Hc + h;
    float*       pp = pre + (size_t)b * Tc * Hc + h;
    const float* qp = q + (size_t)b * Tc * Rc;
    const float* kp = ks + (size_t)b * Tc * Rc;
    const float* lp = lam + (size_t)b * Tc;
    const float bh = bias[h];
    float F[16] = {};
    for (int t = 0; t < Tc; t += 2) {
        float ka[16], qa[16], kb[16], qb[16];
        *(float4*)&ka[0]  = *(const float4*)&kp[t * 16];
        *(float4*)&ka[4]  = *(const float4*)&kp[t * 16 + 4];
        *(float4*)&ka[8]  = *(const float4*)&kp[t * 16 + 8];
        *(float4*)&ka[12] = *(const float4*)&kp[t * 16 + 12];
        *(float4*)&qa[0]  = *(const float4*)&qp[t * 16];
        *(float4*)&qa[4]  = *(const float4*)&qp[t * 16 + 4];
        *(float4*)&qa[8]  = *(const float4*)&qp[t * 16 + 8];
        *(float4*)&qa[12] = *(const float4*)&qp[t * 16 + 12];
        *(float4*)&kb[0]  = *(const float4*)&kp[(t + 1) * 16];
        *(float4*)&kb[4]  = *(const float4*)&kp[(t + 1) * 16 + 4];
        *(float4*)&kb[8]  = *(const float4*)&kp[(t + 1) * 16 + 8];
        *(float4*)&kb[12] = *(const float4*)&kp[(t + 1) * 16 + 12];
        *(float4*)&qb[0]  = *(const float4*)&qp[(t + 1) * 16];
        *(float4*)&qb[4]  = *(const float4*)&qp[(t + 1) * 16 + 4];
        *(float4*)&qb[8]  = *(const float4*)&qp[(t + 1) * 16 + 8];
        *(float4*)&qb[12] = *(const float4*)&qp[(t + 1) * 16 + 12];
        const float l0 = lp[t], l1 = lp[t + 1];
        const float v0 = vp[(size_t)t * Hc], v1 = vp[(size_t)(t + 1) * Hc];
        const float w0 = pp[(size_t)t * Hc], w1 = pp[(size_t)(t + 1) * Hc];
        float r0 = 0.f, r1 = 0.f;
        #pragma unroll
        for (int r = 0; r < 16; ++r) { F[r] = l0 * F[r] + v0 * ka[r]; r0 += F[r] * qa[r]; }
        pp[(size_t)t * Hc] = w0 + r0 + bh;
        #pragma unroll
        for (int r = 0; r < 16; ++r) { F[r] = l1 * F[r] + v1 * kb[r]; r1 += F[r] * qb[r]; }
        pp[(size_t)(t + 1) * Hc] = w1 + r1 + bh;
    }
    float* fo = Ffin + ((size_t)b * Hc + h) * 16;
    *(float4*)&fo[0]  = *(float4*)&F[0];
    *(float4*)&fo[4]  = *(float4*)&F[4];
    *(float4*)&fo[8]  = *(float4*)&F[8];
    *(float4*)&fo[12] = *(float4*)&F[12];
}

// ---------------------------------------------------------------------------
// Serial h-recurrence: h_t = tanh(pre_t + h_{t-1} @ Wh).
// 256 WGs = 64 col-slices x 4 batch-groups. Wh slice in REGISTERS
// (pre-permuted so every wr[] index is compile-time constant).
//
// R4: SELF-SIGNALING DATA. Producers store h + offset, where offset
// alternates {0,+4} between successive writes to the same ping-pong buffer
// (period-4 in t). tanh in [-1,1] => a value in (off-1.5, off+1.5) is
// provably fresh; stale data (other offset) and the 0x7F init (3.4e38)
// fail the check. Consumers poll the data itself per-thread. Removes the
// flag store, the flag poll, the producer's pre-signal vmcnt(0) drain,
// and one barrier per step.
// ---------------------------------------------------------------------------
__global__ __launch_bounds__(256, 1) void rec_kernel(const float* __restrict__ Wh,
    float* __restrict__ out0, float* __restrict__ hfin,
    float* __restrict__ hbuf)
{
    __shared__ float hs[4 * 1024];
    __shared__ float red[16 * 65];
    const int tid = threadIdx.x;
    const int w = blockIdx.x;
    const int sl = w & 63, g = w >> 6;
    const int c0 = sl * 16;
    const int c = tid & 15, part = tid >> 4;   // 16 k-parts x 16 cols
    // Pre-permuted weight load: wr[u*4+j] <-> row (part*64 + ((u+part*4)&15)*4+j)
    float wr[64];
    #pragma unroll
    for (int u = 0; u < 16; ++u) {
        const int i4 = (u + part * 4) & 15;
        #pragma unroll
        for (int j = 0; j < 4; ++j)
            wr[u * 4 + j] = Wh[(size_t)(part * 64 + i4 * 4 + j) * 1024 + c0 + c];
    }
    const int bb = tid >> 4, cc = tid & 15;    // epilogue roles (tid < 64)
    const int bg = g * 4 + bb;

    for (int t = 0; t < Tc; ++t) {
        float* h_rd = hbuf + (t & 1) * (Bc * Hc) + g * 4096;
        float* h_wr = hbuf + ((t + 1) & 1) * (Bc * Hc) + g * 4096;
        const float off_r = ((t >> 1) & 1) ? 4.0f : 0.0f;        // expected
        const float off_w = (((t + 1) >> 1) & 1) ? 4.0f : 0.0f;  // to store
        // Prefetch pre-activation (independent of h) before the poll.
        float pre_t = 0.f;
        size_t oidx = 0;
        if (tid < 64) {
            oidx = ((size_t)bg * Tc + t) * Hc + c0 + cc;
            pre_t = out0[oidx];
        }
        if (t > 0) {
            const float lo = off_r - 1.5f, hi = off_r + 1.5f;
            const float* p0 = h_rd + tid * 4;
            const float* p1 = p0 + 1024;
            const float* p2 = p0 + 2048;
            const float* p3 = p0 + 3072;
            float4 r0, r1, r2, r3;
            while (1) {
                asm volatile(
                    "global_load_dwordx4 %0, %4, off sc0 sc1\n\t"
                    "global_load_dwordx4 %1, %5, off sc0 sc1\n\t"
                    "global_load_dwordx4 %2, %6, off sc0 sc1\n\t"
                    "global_load_dwordx4 %3, %7, off sc0 sc1\n\t"
                    "s_waitcnt vmcnt(0)"
                    : "=&v"(r0), "=&v"(r1), "=&v"(r2), "=&v"(r3)
                    : "v"(p0), "v"(p1), "v"(p2), "v"(p3)
                    : "memory");
                bool ok = r0.x > lo && r0.x < hi && r0.y > lo && r0.y < hi
                       && r0.z > lo && r0.z < hi && r0.w > lo && r0.w < hi
                       && r1.x > lo && r1.x < hi && r1.y > lo && r1.y < hi
                       && r1.z > lo && r1.z < hi && r1.w > lo && r1.w < hi
                       && r2.x > lo && r2.x < hi && r2.y > lo && r2.y < hi
                       && r2.z > lo && r2.z < hi && r2.w > lo && r2.w < hi
                       && r3.x > lo && r3.x < hi && r3.y > lo && r3.y < hi
                       && r3.z > lo && r3.z < hi && r3.w > lo && r3.w < hi;
                if (ok) break;
            }
            r0.x -= off_r; r0.y -= off_r; r0.z -= off_r; r0.w -= off_r;
            r1.x -= off_r; r1.y -= off_r; r1.z -= off_r; r1.w -= off_r;
            r2.x -= off_r; r2.y -= off_r; r2.z -= off_r; r2.w -= off_r;
            r3.x -= off_r; r3.y -= off_r; r3.z -= off_r; r3.w -= off_r;
            *(float4*)&hs[0 * 1024 + tid * 4] = r0;
            *(float4*)&hs[1 * 1024 + tid * 4] = r1;
            *(float4*)&hs[2 * 1024 + tid * 4] = r2;
            *(float4*)&hs[3 * 1024 + tid * 4] = r3;
        } else {
            float4 z = {0.f, 0.f, 0.f, 0.f};
            *(float4*)&hs[0 * 1024 + tid * 4] = z;
            *(float4*)&hs[1 * 1024 + tid * 4] = z;
            *(float4*)&hs[2 * 1024 + tid * 4] = z;
            *(float4*)&hs[3 * 1024 + tid * 4] = z;
        }
        __syncthreads();                       // hs ready
        float a0 = 0.f, a1 = 0.f, a2 = 0.f, a3 = 0.f;
        #pragma unroll
        for (int u = 0; u < 16; ++u) {
            const int i4 = (u + part * 4) & 15;    // bank stagger across parts
            float4 x0 = *(const float4*)&hs[0 * 1024 + part * 64 + i4 * 4];
            float4 x1 = *(const float4*)&hs[1 * 1024 + part * 64 + i4 * 4];
            float4 x2 = *(const float4*)&hs[2 * 1024 + part * 64 + i4 * 4];
            float4 x3 = *(const float4*)&hs[3 * 1024 + part * 64 + i4 * 4];
            const float w0 = wr[u * 4 + 0], w1 = wr[u * 4 + 1];
            const float w2 = wr[u * 4 + 2], w3 = wr[u * 4 + 3];
            a0 += x0.x * w0 + x0.y * w1 + x0.z * w2 + x0.w * w3;
            a1 += x1.x * w0 + x1.y * w1 + x1.z * w2 + x1.w * w3;
            a2 += x2.x * w0 + x2.y * w1 + x2.z * w2 + x2.w * w3;
            a3 += x3.x * w0 + x3.y * w1 + x3.z * w2 + x3.w * w3;
        }
        red[part * 65 + 0  + c] = a0;
        red[part * 65 + 16 + c] = a1;
        red[part * 65 + 32 + c] = a2;
        red[part * 65 + 48 + c] = a3;
        __syncthreads();                       // red ready (also: all done with hs)
        if (tid < 64) {
            float sum = 0.f;
            #pragma unroll
            for (int p = 0; p < 16; ++p) sum += red[p * 65 + tid];
            float hv = tanhf(pre_t + sum);
            out0[oidx] = hv;                   // cached store (final output)
            if (t == Tc - 1) hfin[(size_t)bg * Hc + c0 + cc] = hv;
            float sv = hv + off_w;             // self-signaling store, no wait
            float* hp = h_wr + bb * 1024 + c0 + cc;
            asm volatile(
                "global_store_dword %0, %1, off sc0 sc1"
                :: "v"(hp), "v"(sv) : "memory");
        }
    }
}

// ---------------------------------------------------------------------------
extern "C" void kernel_launch(void* const* d_in, const int* in_sizes, int n_in,
                              void* d_out, int out_size, void* d_ws, size_t ws_size,
                              hipStream_t stream)
{
    const float* x    = (const float*)d_in[0];
    const float* Wx   = (const float*)d_in[1];
    const float* Wh   = (const float*)d_in[2];
    const float* Wq   = (const float*)d_in[3];
    const float* Wk   = (const float*)d_in[4];
    const float* Wv   = (const float*)d_in[5];
    const float* Wd   = (const float*)d_in[6];
    const float* bias = (const float*)d_in[7];
    const float* bd   = (const float*)d_in[8];

    float* out0 = (float*)d_out;                    // (B,T,H)
    float* hfin = out0 + (size_t)Bc * Tc * Hc;      // (B,H)
    float* Ffin = hfin + (size_t)Bc * Hc;           // (B,H,R)

    float* wsf  = (float*)d_ws;
    float* v    = wsf;                               // B*T*H
    float* q    = v + (size_t)Bc * Tc * Hc;          // B*T*R
    float* k    = q + (size_t)Bc * Tc * Rc;          // B*T*R
    float* lam  = k + (size_t)Bc * Tc * Rc;          // B*T
    float* hbuf = lam + (size_t)Bc * Tc;             // 2 * B*H ping-pong

    // 0x7F7F7F7F == 3.39e38f: invalid under both offsets -> poll-safe init.
    hipMemsetAsync(hbuf, 0x7F, 2 * (size_t)Bc * Hc * sizeof(float), stream);

    dim3 gg(256, 16);
    gemm_xw<<<gg, 256, 0, stream>>>(x, Wx, out0);   // xw -> out0
    gemm_xw<<<gg, 256, 0, stream>>>(x, Wv, v);      // v  -> ws
    qkl_kernel<<<4096, 256, 0, stream>>>(x, Wq, Wk, Wd, bd, q, k, lam);
    scan_kernel<<<64, 256, 0, stream>>>(v, q, k, lam, bias, out0, Ffin);
    rec_kernel<<<256, 256, 0, stream>>>(Wh, out0, hfin, hbuf);
}